// Round 8
// baseline (317.757 us; speedup 1.0000x reference)
//
#include <hip/hip_runtime.h>

// conv3d(8ci->8co, 3x3x3, same) + relu/leaky/gelu/sigmoid + bias, via bf16 MFMA.
//
// GEMM view, DUAL-D (R12): m = w-pos (16), n = co + 8*s (s = output slice d+s),
// k = tap'*8+ci, tap' over kd' in [0,4) x (kh,kw) = 36 taps = 9 K=32 steps.
// LDS [slice][h][w][ci] bf16, 6-slot ring, slice s -> slot (s+1)%6.
//
// History: R9 = 117 us (FETCH 160/WRITE 131 MB, Mfma 9.8, VALU 42.5, Occ 37).
// R10 (d-split x4): 235 us, cache thrash -- dispatch pattern is untouchable.
// R11 (T14-in-iteration + sched_barrier pin): 155 us -- pin defeats compiler.
// R12 (dual-d): 114 us. MFMA -36%, VALU -32%, barriers halved... time -2.6%.
//   => runtime INSENSITIVE to compute: latency-bound. Per-CU: 8550 cyc/iter,
//   ~3000 counted issue. Culprits: (a) fused stage puts ds_writes before
//   ds_reads (alias unprovable -> reads serialize behind HBM loads);
//   (b) __syncthreads emits s_waitcnt vmcnt(0) before s_barrier -> NO load
//   survives a barrier; every iteration pays a full exposed HBM round trip.
//
// R13 (this): cross-iteration prefetch + weak barrier (guide T3/T4).
// Iteration d: [MFMA reads slices d-1..d+2] [pack+ds_write slices d+3,d+4
// from regs loaded LAST iteration -- vmcnt wait free] [issue loads d+5,d+6]
// [act+stores] [s_waitcnt lgkmcnt(0) + raw s_barrier -- vmcnt NOT drained].
// LDS hazards need only lgkm+barrier (no cross-thread global communication).
// Slot ring identical to R12 (reads (d..d+3)%6, writes (d+4),(d+5)%6 disjoint;
// write-after-read separated by >=1 barrier).

#define CIN 8
#define COUT 8
#define DDIM 32
#define HDIM 128
#define WDIM 128
#define HWSZ (HDIM * WDIM)           // 16384
#define CISTR (DDIM * HWSZ)          // x ci stride in floats

#define ROWPTS 66                    // w = -1..64 (64-wide tile + halo)
#define ROWB   (ROWPTS * 16)         // 1056 B
#define SROWS  6                     // h = -1..4 (4-high tile + halo)
#define SLICEPTS (SROWS * ROWPTS)    // 396 points
#define SLICEB (SROWS * ROWB)        // 6336 B
#define NSLOT 6
#define LDSB (NSLOT * SLICEB)        // 38016 B -> 4 blocks/CU
#define ND 16                        // output d per block (dsplit = 2); step 2

typedef short short8 __attribute__((ext_vector_type(8)));
typedef float floatx4 __attribute__((ext_vector_type(4)));

static __device__ __forceinline__ unsigned f2bf(float f) {
    unsigned u = __builtin_bit_cast(unsigned, f);
    return (u + 0x7FFFu + ((u >> 16) & 1u)) >> 16;   // RTN-even bf16
}

static __device__ __forceinline__ float act(float v, float bco) {
    float y = fmaxf(v, 0.f);                         // relu (leaky is identity after relu)
    float t = 0.7978845608028654f * (y + 0.044715f * y * y * y);
    float e = __builtin_amdgcn_exp2f(2.8853900817779268f * t);       // e^{2t}
    float g = y - y * __builtin_amdgcn_rcpf(1.f + e);                // tanh-gelu
    float s = __builtin_amdgcn_rcpf(1.f + __builtin_amdgcn_exp2f(-1.4426950408889634f * g));
    return s + bco;                                  // sigmoid + channel bias
}

// Block: 256 threads = 4 waves; wave w handles output h-row (h0+w), 4 w-chunks of 16.
// Grid: 2 wb * 32 hb * 8 b * 2 dsplit = 1024 blocks; 8 dual-d iterations per block.
__global__ __launch_bounds__(256, 4) void conv3d_mfma_kernel(
    const float* __restrict__ x,
    const float* __restrict__ wgt,
    const float* __restrict__ bias,
    float* __restrict__ out)
{
    __shared__ __align__(16) char lds[LDSB];

    const int tid  = threadIdx.x;
    const int lane = tid & 63;
    const int wid  = tid >> 6;        // wave id = local h row 0..3
    const int m    = lane & 15;       // A-row (w pos); also n = co + 8*ds for B, C/D
    const int g    = lane >> 4;       // k-group 0..3
    const int co   = m & 7;           // output channel
    const int ds   = m >> 3;          // output d offset s in {0,1}

    int bx = blockIdx.x;
    const int wb = bx & 1;   bx >>= 1;
    const int hb = bx & 31;  bx >>= 5;
    const int b  = bx & 7;   bx >>= 3;
    const int d0 = bx * ND;           // d split: d0 in {0,16}
    const int h0 = hb * 4;
    const int W0 = wb * 64;
    const int dlim = d0 + ND;         // last slice index ever needed

    const float* xb = x + (size_t)b * CIN * CISTR;

    // ---- B fragments (weights), 9 k-steps over 36 taps', n = co+8*ds ----
    short8 bw[9];
    unsigned aoff[9];                 // per-lane A byte offset: kd'*SLICEB + spatial
    #pragma unroll
    for (int t = 0; t < 9; ++t) {
        const int tap = 4 * t + g;    // 0..35, no pad
        const int kd = tap / 9, r = tap % 9;
        const int kh = r / 3, kw = r % 3;
        const int kds = kd - ds;
        const bool wok = (kds >= 0) & (kds < 3);
        #pragma unroll
        for (int j = 0; j < 8; ++j) {
            float v = wok ? wgt[(co * CIN + j) * 27 + kds * 9 + kh * 3 + kw] : 0.f;
            bw[t][j] = (short)f2bf(v);
        }
        aoff[t] = (unsigned)(kd * SLICEB + (kh + wid) * ROWB + (m + kw) * 16);
    }
    const float bco = bias[co];

    // ---- staging geometry, d-invariant: 2 points per thread (p = tid, tid+256) ----
    int  soff[2];
    bool okhw[2];
    int  ldso[2];
    #pragma unroll
    for (int i = 0; i < 2; ++i) {
        const int p  = tid + 256 * i;
        const int hh = p / ROWPTS, ww = p - hh * ROWPTS;
        const int hg = h0 + hh - 1, wg = W0 + ww - 1;
        okhw[i] = (p < SLICEPTS) & ((unsigned)hg < HDIM) & ((unsigned)wg < WDIM);
        soff[i] = hg * WDIM + wg;          // junk when !okhw -- never dereferenced
        ldso[i] = p * 16;
    }

    // ---- split staging primitives (no scheduling pragmas anywhere) ----
    auto stage_load = [&](int dg, float (&r)[2][8]) {       // global -> regs
        const float* xs = xb + (size_t)dg * HWSZ;
        const bool din = (unsigned)dg < DDIM;
        #pragma unroll
        for (int i = 0; i < 2; ++i) {
            const bool ok = okhw[i] & din;
            const float* src = xs + soff[i];
            #pragma unroll
            for (int c = 0; c < 8; ++c)
                r[i][c] = ok ? src[c * CISTR] : 0.f;   // coalesced per-ci loads
        }
    };
    auto stage_write = [&](int dg, const float (&r)[2][8]) { // regs -> LDS
        char* sb = lds + ((dg + 1) % NSLOT) * SLICEB;
        #pragma unroll
        for (int i = 0; i < 2; ++i) {
            const int p = tid + 256 * i;
            if (p < SLICEPTS) {
                unsigned q[4];
                #pragma unroll
                for (int c = 0; c < 4; ++c)
                    q[c] = f2bf(r[i][2 * c]) | (f2bf(r[i][2 * c + 1]) << 16);
                *(int4*)(sb + ldso[i]) = make_int4(q[0], q[1], q[2], q[3]);
            }
        }
    };
    auto stage = [&](int dg) {                               // fused (prologue only)
        float r[2][8];
        stage_load(dg, r);
        stage_write(dg, r);
    };

    // ---- prologue: slices d0-1..d0+2 staged; prefetch loads for d0+3,d0+4 ----
    stage(d0 - 1); stage(d0); stage(d0 + 1); stage(d0 + 2);
    float rA[2][8], rB[2][8];          // in-flight slice pair (d+3, d+4)
    stage_load(d0 + 3, rA);
    stage_load(d0 + 4, rB);
    asm volatile("s_waitcnt lgkmcnt(0)" ::: "memory");
    __builtin_amdgcn_s_barrier();      // prefetch loads stay in flight

    // slot of slice s is (s+1)%6; iter d reads slices d-1..d+2 -> slots (d..d+3)%6.
    unsigned sdB = (unsigned)(d0 % NSLOT) * SLICEB;

    for (int d = d0; d < dlim; d += 2) {
        // 1. MFMA over slots (d..d+3)%6 -- first, so ds_reads never order
        //    behind this iteration's ds_writes.
        floatx4 acc0 = {0,0,0,0}, acc1 = {0,0,0,0}, acc2 = {0,0,0,0}, acc3 = {0,0,0,0};
        #pragma unroll
        for (int t = 0; t < 9; ++t) {
            unsigned off = sdB + aoff[t];
            off = (off >= (unsigned)LDSB) ? off - (unsigned)LDSB : off;
            const char* ap = lds + off;
            short8 a0 = __builtin_bit_cast(short8, *(const int4*)(ap      ));
            short8 a1 = __builtin_bit_cast(short8, *(const int4*)(ap + 256));
            short8 a2 = __builtin_bit_cast(short8, *(const int4*)(ap + 512));
            short8 a3 = __builtin_bit_cast(short8, *(const int4*)(ap + 768));
            acc0 = __builtin_amdgcn_mfma_f32_16x16x32_bf16(a0, bw[t], acc0, 0, 0, 0);
            acc1 = __builtin_amdgcn_mfma_f32_16x16x32_bf16(a1, bw[t], acc1, 0, 0, 0);
            acc2 = __builtin_amdgcn_mfma_f32_16x16x32_bf16(a2, bw[t], acc2, 0, 0, 0);
            acc3 = __builtin_amdgcn_mfma_f32_16x16x32_bf16(a3, bw[t], acc3, 0, 0, 0);
        }

        // 2. pack + ds_write slices d+3,d+4 from regs loaded LAST iteration:
        //    the auto vmcnt wait is ~one full iteration old => free.
        if (d + 4 <= dlim) { stage_write(d + 3, rA); stage_write(d + 4, rB); }

        // 3. fire prefetch loads for slices d+5,d+6 (consumed next iteration;
        //    they will cross the weak barrier still in flight).
        if (d + 6 <= dlim) { stage_load(d + 5, rA); stage_load(d + 6, rB); }

        // 4. epilogue: col n = co+8*ds, rows g*4+reg -> 4 consecutive w.
        {
            float* op = out + ((size_t)(b * COUT + co) * DDIM + (d + ds)) * HWSZ
                            + (h0 + wid) * WDIM + W0 + g * 4;
            *(float4*)(op)      = make_float4(act(acc0[0],bco), act(acc0[1],bco), act(acc0[2],bco), act(acc0[3],bco));
            *(float4*)(op + 16) = make_float4(act(acc1[0],bco), act(acc1[1],bco), act(acc1[2],bco), act(acc1[3],bco));
            *(float4*)(op + 32) = make_float4(act(acc2[0],bco), act(acc2[1],bco), act(acc2[2],bco), act(acc2[3],bco));
            *(float4*)(op + 48) = make_float4(act(acc3[0],bco), act(acc3[1],bco), act(acc3[2],bco), act(acc3[3],bco));
        }

        // 5. weak barrier: LDS ordering only (lgkm), vmcnt NOT drained.
        asm volatile("s_waitcnt lgkmcnt(0)" ::: "memory");
        __builtin_amdgcn_s_barrier();

        sdB += 2 * SLICEB;
        if (sdB >= (unsigned)LDSB) sdB -= (unsigned)LDSB;
    }
}

extern "C" void kernel_launch(void* const* d_in, const int* in_sizes, int n_in,
                              void* d_out, int out_size, void* d_ws, size_t ws_size,
                              hipStream_t stream) {
    const float* x    = (const float*)d_in[0];
    const float* wgt  = (const float*)d_in[1];
    const float* bias = (const float*)d_in[2];
    float* out = (float*)d_out;

    dim3 grid(2 * 32 * 8 * 2);   // wb * hb * b * dsplit = 1024
    dim3 block(256);
    conv3d_mfma_kernel<<<grid, block, 0, stream>>>(x, wgt, bias, out);
}

// Round 9
// 307.978 us; speedup vs baseline: 1.0318x; 1.0318x over previous
//
#include <hip/hip_runtime.h>

// conv3d(8ci->8co, 3x3x3, same) + relu/leaky/gelu/sigmoid + bias, via bf16 MFMA.
//
// GEMM view, DUAL-D (R12): m = w-pos (16), n = co + 8*s (s = output slice d+s),
// k = tap'*8+ci, tap' over kd' in [0,4) x (kh,kw) = 36 taps = 9 K=32 steps.
// LDS [slice][h][w][ci] bf16, 6-slot ring, slice s -> slot (s+1)%6.
//
// History: R9 117us | R10 d-split+regprefetch 235us | R11 T14+pin 155us |
// R12 dual-d 114us (best) | R13 cross-barrier prefetch 150us.
// R13/R10 post-mortem: symmetric FETCH/WRITE growth (+14/+18, +135/+84 MB)
// with unchanged epilogue = SCRATCH SPILLS of the 32 f32 carried across the
// barrier (VGPR_Count pinned at 64). R11 (within-iteration temps) was clean.
// => cross-barrier register carry is forbidden; R13's schedule was never
// really tested.
//
// R12 stall model (no pipe >33% busy, time = traffic/2.5TB/s): per iteration
// (a) fused stage packs right after load-issue -> exposed ~900cy vmcnt wait,
// and unprovable LDS aliasing orders ALL stage ds_writes BEFORE MFMA ds_reads;
// (b) __syncthreads drains vmcnt(0) incl. 16KB of output stores -> store-ack
// round trip on congested HBM every iteration.
//
// R14 (this): within-iteration reorder + weak barrier, NO cross-barrier regs,
// NO sched pins: [issue loads d+3,d+4] [MFMA (ds_reads first in DS order)]
// [pack: vmcnt wait hidden under MFMA] [ds_write d+3,d+4] [act + stores]
// [s_waitcnt lgkmcnt(0); s_barrier]  -- stores stay in flight across the
// barrier (nothing reads out); loads are consumed pre-barrier; vmcnt ordering
// drains old stores during next iteration's pack wait. Ring invariant: reads
// slots {k..k+3}%6, writes {k+4,k+5}%6 -- disjoint every iteration.

#define CIN 8
#define COUT 8
#define DDIM 32
#define HDIM 128
#define WDIM 128
#define HWSZ (HDIM * WDIM)           // 16384
#define CISTR (DDIM * HWSZ)          // x ci stride in floats

#define ROWPTS 66                    // w = -1..64 (64-wide tile + halo)
#define ROWB   (ROWPTS * 16)         // 1056 B
#define SROWS  6                     // h = -1..4 (4-high tile + halo)
#define SLICEPTS (SROWS * ROWPTS)    // 396 points
#define SLICEB (SROWS * ROWB)        // 6336 B
#define NSLOT 6
#define LDSB (NSLOT * SLICEB)        // 38016 B -> 4 blocks/CU
#define ND 16                        // output d per block (dsplit = 2); step 2

typedef short short8 __attribute__((ext_vector_type(8)));
typedef float floatx4 __attribute__((ext_vector_type(4)));

static __device__ __forceinline__ unsigned f2bf(float f) {
    unsigned u = __builtin_bit_cast(unsigned, f);
    return (u + 0x7FFFu + ((u >> 16) & 1u)) >> 16;   // RTN-even bf16
}

static __device__ __forceinline__ float act(float v, float bco) {
    float y = fmaxf(v, 0.f);                         // relu (leaky is identity after relu)
    float t = 0.7978845608028654f * (y + 0.044715f * y * y * y);
    float e = __builtin_amdgcn_exp2f(2.8853900817779268f * t);       // e^{2t}
    float g = y - y * __builtin_amdgcn_rcpf(1.f + e);                // tanh-gelu
    float s = __builtin_amdgcn_rcpf(1.f + __builtin_amdgcn_exp2f(-1.4426950408889634f * g));
    return s + bco;                                  // sigmoid + channel bias
}

// Block: 256 threads = 4 waves; wave w handles output h-row (h0+w), 4 w-chunks of 16.
// Grid: 2 wb * 32 hb * 8 b * 2 dsplit = 1024 blocks; 8 dual-d iterations per block.
__global__ __launch_bounds__(256, 4) void conv3d_mfma_kernel(
    const float* __restrict__ x,
    const float* __restrict__ wgt,
    const float* __restrict__ bias,
    float* __restrict__ out)
{
    __shared__ __align__(16) char lds[LDSB];

    const int tid  = threadIdx.x;
    const int lane = tid & 63;
    const int wid  = tid >> 6;        // wave id = local h row 0..3
    const int m    = lane & 15;       // A-row (w pos); also n = co + 8*ds for B, C/D
    const int g    = lane >> 4;       // k-group 0..3
    const int co   = m & 7;           // output channel
    const int ds   = m >> 3;          // output d offset s in {0,1}

    int bx = blockIdx.x;
    const int wb = bx & 1;   bx >>= 1;
    const int hb = bx & 31;  bx >>= 5;
    const int b  = bx & 7;   bx >>= 3;
    const int d0 = bx * ND;           // d split: d0 in {0,16}
    const int h0 = hb * 4;
    const int W0 = wb * 64;
    const int dlim = d0 + ND;         // last slice index ever needed

    const float* xb = x + (size_t)b * CIN * CISTR;

    // ---- B fragments (weights), 9 k-steps over 36 taps', n = co+8*ds ----
    short8 bw[9];
    unsigned aoff[9];                 // per-lane A byte offset: kd'*SLICEB + spatial
    #pragma unroll
    for (int t = 0; t < 9; ++t) {
        const int tap = 4 * t + g;    // 0..35, no pad
        const int kd = tap / 9, r = tap % 9;
        const int kh = r / 3, kw = r % 3;
        const int kds = kd - ds;
        const bool wok = (kds >= 0) & (kds < 3);
        #pragma unroll
        for (int j = 0; j < 8; ++j) {
            float v = wok ? wgt[(co * CIN + j) * 27 + kds * 9 + kh * 3 + kw] : 0.f;
            bw[t][j] = (short)f2bf(v);
        }
        aoff[t] = (unsigned)(kd * SLICEB + (kh + wid) * ROWB + (m + kw) * 16);
    }
    const float bco = bias[co];

    // ---- staging geometry, d-invariant: 2 points per thread (p = tid, tid+256) ----
    int  soff[2];
    bool okhw[2];
    int  ldso[2];
    #pragma unroll
    for (int i = 0; i < 2; ++i) {
        const int p  = tid + 256 * i;
        const int hh = p / ROWPTS, ww = p - hh * ROWPTS;
        const int hg = h0 + hh - 1, wg = W0 + ww - 1;
        okhw[i] = (p < SLICEPTS) & ((unsigned)hg < HDIM) & ((unsigned)wg < WDIM);
        soff[i] = hg * WDIM + wg;          // junk when !okhw -- never dereferenced
        ldso[i] = p * 16;
    }

    // ---- staging primitives; all temps are within-iteration only ----
    auto stage_load = [&](int dg, float (&r)[2][8]) {       // global -> regs
        const float* xs = xb + (size_t)dg * HWSZ;
        const bool din = (unsigned)dg < DDIM;
        #pragma unroll
        for (int i = 0; i < 2; ++i) {
            const bool ok = okhw[i] & din;
            const float* src = xs + soff[i];
            #pragma unroll
            for (int c = 0; c < 8; ++c)
                r[i][c] = ok ? src[c * CISTR] : 0.f;   // coalesced per-ci loads
        }
    };
    auto stage_write = [&](int dg, const float (&r)[2][8]) { // pack + LDS write
        char* sb = lds + ((dg + 1) % NSLOT) * SLICEB;
        #pragma unroll
        for (int i = 0; i < 2; ++i) {
            const int p = tid + 256 * i;
            if (p < SLICEPTS) {
                unsigned q[4];
                #pragma unroll
                for (int c = 0; c < 4; ++c)
                    q[c] = f2bf(r[i][2 * c]) | (f2bf(r[i][2 * c + 1]) << 16);
                *(int4*)(sb + ldso[i]) = make_int4(q[0], q[1], q[2], q[3]);
            }
        }
    };
    auto stage = [&](int dg) {                               // fused (prologue only)
        float r[2][8];
        stage_load(dg, r);
        stage_write(dg, r);
    };

    // ---- prologue: slices d0-1..d0+2; full drain once ----
    stage(d0 - 1); stage(d0); stage(d0 + 1); stage(d0 + 2);
    __syncthreads();

    // slot of slice s is (s+1)%6; iter d reads slices d-1..d+2 -> slots (d..d+3)%6.
    unsigned sdB = (unsigned)(d0 % NSLOT) * SLICEB;

    for (int d = d0; d < dlim; d += 2) {
        const bool do_stage = (d + 4 <= dlim);   // false only on the last iteration

        // 1. issue next-pair loads (slices d+3,d+4); consumed at step 3.
        float rA[2][8], rB[2][8];
        if (do_stage) { stage_load(d + 3, rA); stage_load(d + 4, rB); }

        // 2. MFMA over slots (d..d+3)%6 -- ds_reads precede this iteration's
        //    ds_writes in DS order (compiler can't reorder unprovable aliases).
        floatx4 acc0 = {0,0,0,0}, acc1 = {0,0,0,0}, acc2 = {0,0,0,0}, acc3 = {0,0,0,0};
        #pragma unroll
        for (int t = 0; t < 9; ++t) {
            unsigned off = sdB + aoff[t];
            off = (off >= (unsigned)LDSB) ? off - (unsigned)LDSB : off;
            const char* ap = lds + off;
            short8 a0 = __builtin_bit_cast(short8, *(const int4*)(ap      ));
            short8 a1 = __builtin_bit_cast(short8, *(const int4*)(ap + 256));
            short8 a2 = __builtin_bit_cast(short8, *(const int4*)(ap + 512));
            short8 a3 = __builtin_bit_cast(short8, *(const int4*)(ap + 768));
            acc0 = __builtin_amdgcn_mfma_f32_16x16x32_bf16(a0, bw[t], acc0, 0, 0, 0);
            acc1 = __builtin_amdgcn_mfma_f32_16x16x32_bf16(a1, bw[t], acc1, 0, 0, 0);
            acc2 = __builtin_amdgcn_mfma_f32_16x16x32_bf16(a2, bw[t], acc2, 0, 0, 0);
            acc3 = __builtin_amdgcn_mfma_f32_16x16x32_bf16(a3, bw[t], acc3, 0, 0, 0);
        }

        // 3. pack (vmcnt wait hidden under the MFMA block) + ds_write d+3,d+4
        //    into slots (d+4)%6,(d+5)%6 -- disjoint from this iter's read slots.
        if (do_stage) { stage_write(d + 3, rA); stage_write(d + 4, rB); }

        // 4. epilogue: col n = co+8*ds, rows g*4+reg -> 4 consecutive w.
        {
            float* op = out + ((size_t)(b * COUT + co) * DDIM + (d + ds)) * HWSZ
                            + (h0 + wid) * WDIM + W0 + g * 4;
            *(float4*)(op)      = make_float4(act(acc0[0],bco), act(acc0[1],bco), act(acc0[2],bco), act(acc0[3],bco));
            *(float4*)(op + 16) = make_float4(act(acc1[0],bco), act(acc1[1],bco), act(acc1[2],bco), act(acc1[3],bco));
            *(float4*)(op + 32) = make_float4(act(acc2[0],bco), act(acc2[1],bco), act(acc2[2],bco), act(acc2[3],bco));
            *(float4*)(op + 48) = make_float4(act(acc3[0],bco), act(acc3[1],bco), act(acc3[2],bco), act(acc3[3],bco));
        }

        // 5. weak barrier: LDS ordering only; output stores stay in flight
        //    (vmcnt deliberately NOT drained -- nothing reads out).
        if (d + 2 < dlim) {
            asm volatile("s_waitcnt lgkmcnt(0)" ::: "memory");
            __builtin_amdgcn_s_barrier();
        }

        sdB += 2 * SLICEB;
        if (sdB >= (unsigned)LDSB) sdB -= (unsigned)LDSB;
    }
}

extern "C" void kernel_launch(void* const* d_in, const int* in_sizes, int n_in,
                              void* d_out, int out_size, void* d_ws, size_t ws_size,
                              hipStream_t stream) {
    const float* x    = (const float*)d_in[0];
    const float* wgt  = (const float*)d_in[1];
    const float* bias = (const float*)d_in[2];
    float* out = (float*)d_out;

    dim3 grid(2 * 32 * 8 * 2);   // wb * hb * b * dsplit = 1024
    dim3 block(256);
    conv3d_mfma_kernel<<<grid, block, 0, stream>>>(x, wgt, bias, out);
}